// Round 1
// baseline (241.239 us; speedup 1.0000x reference)
//
#include <hip/hip_runtime.h>
#include <math.h>

// PerturbNet: N=1,048,576 independent tiny MLPs, H=5, all fp32.
//   h1 = elu(x*W1 + b1)            (H)
//   h2 = elu(W2 @ h1 + b2)         (H), W2 is (out,in) per model
//   out = dot(h2, W3) + b3         (1)
// Memory-bound: 188 B in + 4 B out per model -> ~201 MB total, floor ~32 us.
// Strategy: LDS-stage each block's 256 models with coalesced float4 loads,
// then thread-per-model compute from LDS (odd strides 5/25 -> <=2-way bank
// aliasing, free on gfx950).

#define H 5
#define MPB 256   // models per block == blockDim.x

__global__ __launch_bounds__(256) void perturbnet_kernel(
    const float* __restrict__ x,
    const float* __restrict__ W1,
    const float* __restrict__ b1,
    const float* __restrict__ W2,
    const float* __restrict__ b2,
    const float* __restrict__ W3,
    const float* __restrict__ b3,
    float* __restrict__ out,
    int N)
{
    __shared__ __align__(16) float sX [MPB];
    __shared__ __align__(16) float sW1[MPB * H];
    __shared__ __align__(16) float sB1[MPB * H];
    __shared__ __align__(16) float sW2[MPB * H * H];
    __shared__ __align__(16) float sB2[MPB * H];
    __shared__ __align__(16) float sW3[MPB * H];
    __shared__ __align__(16) float sB3[MPB];

    const int tid = threadIdx.x;
    const int blockBase = blockIdx.x * MPB;

    if (blockBase + MPB <= N) {
        // ---- fast path: full block, fully coalesced float4 staging ----
        // All global offsets are multiples of 16 bytes (MPB*k*4 with k in
        // {1,5,25}); all float counts divisible by 4.
        {
            const float4* s;
            float4* d;

            s = reinterpret_cast<const float4*>(x + blockBase);
            d = reinterpret_cast<float4*>(sX);
            for (int i = tid; i < (MPB) / 4; i += MPB) d[i] = s[i];

            s = reinterpret_cast<const float4*>(W1 + (size_t)blockBase * H);
            d = reinterpret_cast<float4*>(sW1);
            for (int i = tid; i < (MPB * H) / 4; i += MPB) d[i] = s[i];

            s = reinterpret_cast<const float4*>(b1 + (size_t)blockBase * H);
            d = reinterpret_cast<float4*>(sB1);
            for (int i = tid; i < (MPB * H) / 4; i += MPB) d[i] = s[i];

            s = reinterpret_cast<const float4*>(W2 + (size_t)blockBase * H * H);
            d = reinterpret_cast<float4*>(sW2);
            for (int i = tid; i < (MPB * H * H) / 4; i += MPB) d[i] = s[i];

            s = reinterpret_cast<const float4*>(b2 + (size_t)blockBase * H);
            d = reinterpret_cast<float4*>(sB2);
            for (int i = tid; i < (MPB * H) / 4; i += MPB) d[i] = s[i];

            s = reinterpret_cast<const float4*>(W3 + (size_t)blockBase * H);
            d = reinterpret_cast<float4*>(sW3);
            for (int i = tid; i < (MPB * H) / 4; i += MPB) d[i] = s[i];

            s = reinterpret_cast<const float4*>(b3 + blockBase);
            d = reinterpret_cast<float4*>(sB3);
            for (int i = tid; i < (MPB) / 4; i += MPB) d[i] = s[i];
        }
        __syncthreads();

        // ---- compute: one thread per model, all operands in LDS ----
        const float xv = sX[tid];

        float h1[H];
        #pragma unroll
        for (int h = 0; h < H; ++h) {
            float v = fmaf(xv, sW1[tid * H + h], sB1[tid * H + h]);
            h1[h] = v > 0.0f ? v : (__expf(v) - 1.0f);
        }

        float h2[H];
        #pragma unroll
        for (int o = 0; o < H; ++o) {
            float acc = sB2[tid * H + o];
            #pragma unroll
            for (int h = 0; h < H; ++h)
                acc = fmaf(h1[h], sW2[tid * H * H + o * H + h], acc);
            h2[o] = acc > 0.0f ? acc : (__expf(acc) - 1.0f);
        }

        float acc = sB3[tid];
        #pragma unroll
        for (int o = 0; o < H; ++o)
            acc = fmaf(h2[o], sW3[tid * H + o], acc);

        out[blockBase + tid] = acc;
    } else {
        // ---- tail path (unused at N=1M, kept for generality) ----
        const int i = blockBase + tid;
        if (i < N) {
            const float xv = x[i];
            float h1[H];
            #pragma unroll
            for (int h = 0; h < H; ++h) {
                float v = fmaf(xv, W1[(size_t)i * H + h], b1[(size_t)i * H + h]);
                h1[h] = v > 0.0f ? v : (__expf(v) - 1.0f);
            }
            float h2[H];
            #pragma unroll
            for (int o = 0; o < H; ++o) {
                float acc = b2[(size_t)i * H + o];
                #pragma unroll
                for (int h = 0; h < H; ++h)
                    acc = fmaf(h1[h], W2[(size_t)i * H * H + o * H + h], acc);
                h2[o] = acc > 0.0f ? acc : (__expf(acc) - 1.0f);
            }
            float acc = b3[i];
            #pragma unroll
            for (int o = 0; o < H; ++o)
                acc = fmaf(h2[o], W3[(size_t)i * H + o], acc);
            out[i] = acc;
        }
    }
}

extern "C" void kernel_launch(void* const* d_in, const int* in_sizes, int n_in,
                              void* d_out, int out_size, void* d_ws, size_t ws_size,
                              hipStream_t stream) {
    const float* x  = (const float*)d_in[0];
    const float* W1 = (const float*)d_in[1];
    const float* b1 = (const float*)d_in[2];
    const float* W2 = (const float*)d_in[3];
    const float* b2 = (const float*)d_in[4];
    const float* W3 = (const float*)d_in[5];
    const float* b3 = (const float*)d_in[6];
    float* out = (float*)d_out;

    const int N = in_sizes[0];
    const int grid = (N + MPB - 1) / MPB;
    perturbnet_kernel<<<grid, MPB, 0, stream>>>(x, W1, b1, W2, b2, W3, b3, out, N);
}

// Round 2
// 225.360 us; speedup vs baseline: 1.0705x; 1.0705x over previous
//
#include <hip/hip_runtime.h>
#include <math.h>

// PerturbNet: N=1,048,576 independent tiny MLPs, H=5, fp32.
//   h1 = elu(x*W1 + b1); h2 = elu(W2 @ h1 + b2); out = dot(h2,W3) + b3
//
// R1 post-mortem: staging ALL params in LDS (48 KiB/block) capped occupancy
// at 3 blocks/CU (30%) -> latency-bound at 1.15 TB/s HBM (14%).
// R2: only W2 (stride-100B, would thrash L1 if read direct) goes through LDS
// (25.6 KB/block -> 6 blocks/CU, 24 waves). x/W1/b1/b2/W3/b3 are read
// directly per-thread: stride-4B/20B patterns are ~100% cache-line efficient
// and those loads stay in flight across the staging barrier.

#define H 5
#define MPB 256   // models per block == blockDim.x

__global__ __launch_bounds__(256, 6) void perturbnet_kernel(
    const float* __restrict__ x,
    const float* __restrict__ W1,
    const float* __restrict__ b1,
    const float* __restrict__ W2,
    const float* __restrict__ b2,
    const float* __restrict__ W3,
    const float* __restrict__ b3,
    float* __restrict__ out,
    int N)
{
    __shared__ __align__(16) float sW2[MPB * H * H];   // 25600 B

    const int tid = threadIdx.x;
    const int blockBase = blockIdx.x * MPB;
    const int gid = blockBase + tid;

    if (blockBase + MPB <= N) {
        // ---- direct per-thread loads (coalesced-enough; issue first) ----
        const float xv = x[gid];

        float w1[H], bb1[H], bb2[H], w3[H];
        #pragma unroll
        for (int h = 0; h < H; ++h) w1[h]  = W1[(size_t)gid * H + h];
        #pragma unroll
        for (int h = 0; h < H; ++h) bb1[h] = b1[(size_t)gid * H + h];
        #pragma unroll
        for (int h = 0; h < H; ++h) bb2[h] = b2[(size_t)gid * H + h];
        #pragma unroll
        for (int h = 0; h < H; ++h) w3[h]  = W3[(size_t)gid * H + h];
        const float bb3 = b3[gid];

        // ---- stage W2 through LDS with coalesced float4 loads ----
        // Block's W2 slice: MPB*25 floats = 1600 float4, 16B-aligned
        // (blockBase*100B, blockBase % 256 == 0).
        {
            const float4* s = reinterpret_cast<const float4*>(W2 + (size_t)blockBase * H * H);
            float4* d = reinterpret_cast<float4*>(sW2);
            #pragma unroll
            for (int i = tid; i < (MPB * H * H) / 4; i += MPB) d[i] = s[i];
        }
        __syncthreads();

        // ---- compute ----
        float h1[H];
        #pragma unroll
        for (int h = 0; h < H; ++h) {
            float v = fmaf(xv, w1[h], bb1[h]);
            h1[h] = v > 0.0f ? v : (__expf(v) - 1.0f);
        }

        float h2[H];
        #pragma unroll
        for (int o = 0; o < H; ++o) {
            float acc = bb2[o];
            #pragma unroll
            for (int h = 0; h < H; ++h)
                acc = fmaf(h1[h], sW2[tid * (H * H) + o * H + h], acc);
            h2[o] = acc > 0.0f ? acc : (__expf(acc) - 1.0f);
        }

        float acc = bb3;
        #pragma unroll
        for (int o = 0; o < H; ++o)
            acc = fmaf(h2[o], w3[o], acc);

        out[gid] = acc;
    } else {
        // ---- tail path (unused at N=1M; N is a multiple of 256) ----
        if (gid < N) {
            const float xv = x[gid];
            float h1[H];
            #pragma unroll
            for (int h = 0; h < H; ++h) {
                float v = fmaf(xv, W1[(size_t)gid * H + h], b1[(size_t)gid * H + h]);
                h1[h] = v > 0.0f ? v : (__expf(v) - 1.0f);
            }
            float h2[H];
            #pragma unroll
            for (int o = 0; o < H; ++o) {
                float acc = b2[(size_t)gid * H + o];
                #pragma unroll
                for (int h = 0; h < H; ++h)
                    acc = fmaf(h1[h], W2[(size_t)gid * H * H + o * H + h], acc);
                h2[o] = acc > 0.0f ? acc : (__expf(acc) - 1.0f);
            }
            float acc = b3[gid];
            #pragma unroll
            for (int o = 0; o < H; ++o)
                acc = fmaf(h2[o], W3[(size_t)gid * H + o], acc);
            out[gid] = acc;
        }
    }
}

extern "C" void kernel_launch(void* const* d_in, const int* in_sizes, int n_in,
                              void* d_out, int out_size, void* d_ws, size_t ws_size,
                              hipStream_t stream) {
    const float* x  = (const float*)d_in[0];
    const float* W1 = (const float*)d_in[1];
    const float* b1 = (const float*)d_in[2];
    const float* W2 = (const float*)d_in[3];
    const float* b2 = (const float*)d_in[4];
    const float* W3 = (const float*)d_in[5];
    const float* b3 = (const float*)d_in[6];
    float* out = (float*)d_out;

    const int N = in_sizes[0];
    const int grid = (N + MPB - 1) / MPB;
    perturbnet_kernel<<<grid, MPB, 0, stream>>>(x, W1, b1, W2, b2, W3, b3, out, N);
}